// Round 1
// baseline (288.330 us; speedup 1.0000x reference)
//
#include <hip/hip_runtime.h>

#define NA 1024
#define NBATCH 4
#define NPAIR 523776           // NA*(NA-1)/2
#define PAIR_BLOCKS 2046       // NPAIR / 256 (exact)
#define ATOM_BLOCKS 4          // NA / 256

typedef _Float16 half8 __attribute__((ext_vector_type(8)));
typedef float float4v __attribute__((ext_vector_type(4)));

__device__ __forceinline__ float silu_f(float x) {
    return x * __builtin_amdgcn_rcpf(1.0f + __expf(-x));
}

// ---------------------------------------------------------------------------
// prep: per-batch position mean -> ws, and init out[b] = P*pb2 + N*ab2 (fp32)
// ---------------------------------------------------------------------------
__global__ void prep_kernel(const float* __restrict__ positions,
                            const float* __restrict__ ab2,
                            const float* __restrict__ pb2,
                            float* __restrict__ meanws,
                            float* __restrict__ out) {
    const int b = blockIdx.x;
    const int tid = threadIdx.x;
    const float2* pos = (const float2*)positions + b * NA;
    float sx = 0.f, sy = 0.f;
    for (int t = tid; t < NA; t += 256) {
        float2 p = pos[t];
        sx += p.x; sy += p.y;
    }
#pragma unroll
    for (int off = 32; off > 0; off >>= 1) {
        sx += __shfl_down(sx, off);
        sy += __shfl_down(sy, off);
    }
    __shared__ float rxs[4], rys[4];
    const int w = tid >> 6, lane = tid & 63;
    if (lane == 0) { rxs[w] = sx; rys[w] = sy; }
    __syncthreads();
    if (tid == 0) {
        meanws[b * 2 + 0] = (rxs[0] + rxs[1] + rxs[2] + rxs[3]) * (1.f / NA);
        meanws[b * 2 + 1] = (rys[0] + rys[1] + rys[2] + rys[3]) * (1.f / NA);
        out[b] = (float)NPAIR * pb2[0] + (float)NA * ab2[0];
    }
}

// ---------------------------------------------------------------------------
// fused pair+atom MLP kernel. blockIdx.x < PAIR_BLOCKS -> 256 pairs,
// else -> 256 atoms. 4 waves per block, each wave fully private (no barrier
// until final reduction): 64 rows of features -> L0 MFMA -> silu -> L1 MFMA
// -> silu * W2 accumulated in fp32.
// ---------------------------------------------------------------------------
__global__ __launch_bounds__(256) void mlp_kernel(
    const float* __restrict__ positions,
    const int*   __restrict__ species,
    const float* __restrict__ efield,
    const float* __restrict__ embed,
    const float* __restrict__ aW0, const float* __restrict__ ab0,
    const float* __restrict__ aW1, const float* __restrict__ ab1,
    const float* __restrict__ aW2,
    const float* __restrict__ pW0, const float* __restrict__ pb0,
    const float* __restrict__ pW1, const float* __restrict__ pb1,
    const float* __restrict__ pW2,
    const float* __restrict__ meanws,
    float* __restrict__ out)
{
    const int b    = blockIdx.y;
    const int bx   = blockIdx.x;
    const bool is_pair = (bx < PAIR_BLOCKS);
    const int tid  = threadIdx.x;
    const int lane = tid & 63;
    const int wv   = tid >> 6;
    const int n16  = lane & 15;
    const int quad = lane >> 4;

    // wave-private A/H buffer: 64 rows x 72 f16 (row stride 144B: 16B-aligned,
    // b128 frag reads run at the 8-clk bank floor). cols 0..63 = K (padded).
    __shared__ __attribute__((aligned(16))) _Float16 Abuf[4][64][72];
    _Float16 (*Arows)[72] = Abuf[wv];

    const float Ex = efield[b * 2 + 0];
    const float Ey = efield[b * 2 + 1];
    const float enorm = sqrtf(Ex * Ex + Ey * Ey);

    // ---- build this thread's feature row (fp32 regs, constant-indexed) ----
    float feat[37];
    if (is_pair) {
        int p = bx * 256 + tid;                       // pair index in [0,NPAIR)
        // i = largest i with i*(2047-i)/2 <= p ; exact fp32 (all ints < 2^23)
        float Df = (float)(2047 * 2047 - 8 * p);
        int i = (int)((2047.0f - sqrtf(Df)) * 0.5f);
        i = i < 0 ? 0 : (i > 1022 ? 1022 : i);
        while (i * (2047 - i) / 2 > p) --i;
        while ((i + 1) * (2046 - i) / 2 <= p) ++i;
        int j = p - i * (2047 - i) / 2 + i + 1;

        const float2* pos = (const float2*)positions + b * NA;
        float2 pi = pos[i], pj = pos[j];
        float rx = pi.x - pj.x, ry = pi.y - pj.y;     // mean cancels
        float d  = sqrtf(rx * rx + ry * ry);
        float inv = __builtin_amdgcn_rcpf(fmaxf(d, 1e-12f));
        float edotu = (Ex * rx + Ey * ry) * inv;
        int si = species[b * NA + i];
        int sj = species[b * NA + j];
        feat[0] = rx; feat[1] = ry; feat[2] = d; feat[3] = edotu; feat[4] = enorm;
#pragma unroll
        for (int e = 0; e < 16; e++) feat[5 + e]  = embed[si * 16 + e];
#pragma unroll
        for (int e = 0; e < 16; e++) feat[21 + e] = embed[sj * 16 + e];
    } else {
        int n = (bx - PAIR_BLOCKS) * 256 + tid;       // atom in [0,NA)
        float mx = meanws[b * 2 + 0], my = meanws[b * 2 + 1];
        float2 pn = ((const float2*)positions)[b * NA + n];
        int s = species[b * NA + n];
        feat[0] = pn.x - mx; feat[1] = pn.y - my;
        feat[2] = Ex; feat[3] = Ey; feat[4] = enorm;
#pragma unroll
        for (int e = 0; e < 16; e++) feat[5 + e] = embed[s * 16 + e];
#pragma unroll
        for (int e = 21; e < 37; e++) feat[e] = 0.f;
    }

    // write padded f16 row (cols 0..63; 37.. are zeros) as 8x b128
    {
        half8 chunk;
        half8* rowv = (half8*)(&Arows[lane][0]);
#pragma unroll
        for (int c = 0; c < 8; c++) {
#pragma unroll
            for (int e = 0; e < 8; e++) {
                int k = c * 8 + e;
                chunk[e] = (k < 37) ? (_Float16)feat[k] : (_Float16)0.f;
            }
            rowv[c] = chunk;
        }
    }

    // ---- per-path weight selection ----
    const float* W0  = is_pair ? pW0 : aW0;
    const float* W1  = is_pair ? pW1 : aW1;
    const float* B0  = is_pair ? pb0 : ab0;
    const float* B1  = is_pair ? pb1 : ab1;
    const float* W2  = is_pair ? pW2 : aW2;
    const int    K0  = is_pair ? 37 : 21;

    // B-fragments in registers: B[k = ks*32 + quad*8 + j][n = nt*16 + n16]
    half8 w0f[4][2], w1f[4][2];
#pragma unroll
    for (int nt = 0; nt < 4; nt++) {
#pragma unroll
        for (int ks = 0; ks < 2; ks++) {
#pragma unroll
            for (int jj = 0; jj < 8; jj++) {
                int k = ks * 32 + quad * 8 + jj;
                int col = nt * 16 + n16;
                float w0v = (k < K0) ? W0[k * 64 + col] : 0.f;  // masked: no OOB
                w0f[nt][ks][jj] = (_Float16)w0v;
                w1f[nt][ks][jj] = (_Float16)W1[k * 64 + col];
            }
        }
    }
    float bias0[4], bias1[4], w2c[4];
#pragma unroll
    for (int nt = 0; nt < 4; nt++) {
        bias0[nt] = B0[nt * 16 + n16];
        bias1[nt] = B1[nt * 16 + n16];
        w2c[nt]   = W2[nt * 16 + n16];
    }

    // ---- main: 4 m-tiles of 16 rows; L0 -> silu -> (same rows) -> L1 ----
    float energy = 0.f;
#pragma unroll
    for (int mt = 0; mt < 4; mt++) {
        const _Float16* arow = &Arows[mt * 16 + n16][0];
        half8 a0 = *(const half8*)(arow + quad * 8);
        half8 a1 = *(const half8*)(arow + 32 + quad * 8);

        float4v acc[4];
#pragma unroll
        for (int nt = 0; nt < 4; nt++) {
            float4v c = {bias0[nt], bias0[nt], bias0[nt], bias0[nt]};
            c = __builtin_amdgcn_mfma_f32_16x16x32_f16(a0, w0f[nt][0], c, 0, 0, 0);
            c = __builtin_amdgcn_mfma_f32_16x16x32_f16(a1, w0f[nt][1], c, 0, 0, 0);
            acc[nt] = c;
        }
        // silu, write H1 (f16) back into the same 16 rows
        // C layout: row = quad*4 + r, col = nt*16 + n16
#pragma unroll
        for (int nt = 0; nt < 4; nt++) {
#pragma unroll
            for (int r = 0; r < 4; r++) {
                float hv = silu_f(acc[nt][r]);
                Arows[mt * 16 + quad * 4 + r][nt * 16 + n16] = (_Float16)hv;
            }
        }
        // layer 1 (reads rows just written by this wave; DS pipe is in-order)
        const _Float16* hrow = &Arows[mt * 16 + n16][0];
        half8 h0 = *(const half8*)(hrow + quad * 8);
        half8 h1 = *(const half8*)(hrow + 32 + quad * 8);
        float4v acc2[4];
#pragma unroll
        for (int nt = 0; nt < 4; nt++) {
            float4v c = {bias1[nt], bias1[nt], bias1[nt], bias1[nt]};
            c = __builtin_amdgcn_mfma_f32_16x16x32_f16(h0, w1f[nt][0], c, 0, 0, 0);
            c = __builtin_amdgcn_mfma_f32_16x16x32_f16(h1, w1f[nt][1], c, 0, 0, 0);
            acc2[nt] = c;
        }
        // layer 2 in fp32: sum silu(h2)*W2 over everything (order-free)
#pragma unroll
        for (int nt = 0; nt < 4; nt++) {
#pragma unroll
            for (int r = 0; r < 4; r++)
                energy += silu_f(acc2[nt][r]) * w2c[nt];
        }
    }

    // ---- block reduction -> one atomicAdd per block ----
#pragma unroll
    for (int off = 32; off > 0; off >>= 1)
        energy += __shfl_down(energy, off);
    __shared__ float wsum[4];
    if (lane == 0) wsum[wv] = energy;
    __syncthreads();
    if (tid == 0)
        atomicAdd(&out[b], wsum[0] + wsum[1] + wsum[2] + wsum[3]);
}

// ---------------------------------------------------------------------------
extern "C" void kernel_launch(void* const* d_in, const int* in_sizes, int n_in,
                              void* d_out, int out_size, void* d_ws, size_t ws_size,
                              hipStream_t stream) {
    const float* positions = (const float*)d_in[0];
    const int*   species   = (const int*)  d_in[1];
    const float* efield    = (const float*)d_in[2];
    const float* embed     = (const float*)d_in[3];
    const float* aW0 = (const float*)d_in[4];
    const float* ab0 = (const float*)d_in[5];
    const float* aW1 = (const float*)d_in[6];
    const float* ab1 = (const float*)d_in[7];
    const float* aW2 = (const float*)d_in[8];
    const float* ab2 = (const float*)d_in[9];
    const float* pW0 = (const float*)d_in[10];
    const float* pb0 = (const float*)d_in[11];
    const float* pW1 = (const float*)d_in[12];
    const float* pb1 = (const float*)d_in[13];
    const float* pW2 = (const float*)d_in[14];
    const float* pb2 = (const float*)d_in[15];
    float* outp   = (float*)d_out;
    float* meanws = (float*)d_ws;   // 8 floats

    prep_kernel<<<dim3(NBATCH), dim3(256), 0, stream>>>(positions, ab2, pb2, meanws, outp);
    mlp_kernel<<<dim3(PAIR_BLOCKS + ATOM_BLOCKS, NBATCH), dim3(256), 0, stream>>>(
        positions, species, efield, embed,
        aW0, ab0, aW1, ab1, aW2,
        pW0, pb0, pW1, pb1, pW2,
        meanws, outp);
}

// Round 2
// 167.017 us; speedup vs baseline: 1.7264x; 1.7264x over previous
//
#include <hip/hip_runtime.h>

#define NA 1024
#define NBATCH 4
#define NPAIR 523776           // NA*(NA-1)/2
#define PAIR_TILES 2046        // NPAIR / 256
#define PAIR_BLOCKS 512        // pair blocks, strided tiles {bx, bx+512, ...}
#define GRID_X 513             // + 1 atom block

// ws layout (byte offsets)
#define WS_MEAN 0              // 8 floats (per-batch mean x,y)
#define WS_W0P  64             // 2048 halves: pair W0eff frags
#define WS_W0A  4160           // 2048 halves: atom W0eff frags
#define WS_W1P  8256           // 4096 halves: pair W1 frags
#define WS_W1A  16448          // 4096 halves: atom W1 frags

typedef _Float16 half8 __attribute__((ext_vector_type(8)));
typedef float float4v __attribute__((ext_vector_type(4)));

__device__ __forceinline__ float silu_f(float x) {
    return x * __builtin_amdgcn_rcpf(1.0f + __expf(-x));
}

__device__ __forceinline__ uint32_t pkf16(float a, float b) {
    union { _Float16 h[2]; uint32_t u; } x;
    x.h[0] = (_Float16)a; x.h[1] = (_Float16)b;   // RTNE, matches R1 numerics
    return x.u;
}

// ---------------------------------------------------------------------------
// prep: blocks 0..3 -> per-batch mean + out[b] init; block 4 -> weight packing.
// W0eff rows (K=16 live, padded to 32): 0..4 = raw feature rows, 5 = 0,
// 6..9 = one-hot(i) rows (embed@W0 folded), 10..13 = one-hot(j) rows (pair
// only), 14..31 = 0. Frag order: [(nt*64+lane)*8 + j] = W[(lane>>4)*8+j][nt*16+(lane&15)]
// ---------------------------------------------------------------------------
__global__ void prep_kernel(const float* __restrict__ positions,
                            const float* __restrict__ embed,
                            const float* __restrict__ aW0,
                            const float* __restrict__ aW1,
                            const float* __restrict__ ab2,
                            const float* __restrict__ pW0,
                            const float* __restrict__ pW1,
                            const float* __restrict__ pb2,
                            char* __restrict__ ws,
                            float* __restrict__ out) {
    const int tid = threadIdx.x;
    if (blockIdx.x < 4) {
        const int b = blockIdx.x;
        const float2* pos = (const float2*)positions + b * NA;
        float sx = 0.f, sy = 0.f;
        for (int t = tid; t < NA; t += 256) {
            float2 p = pos[t];
            sx += p.x; sy += p.y;
        }
#pragma unroll
        for (int off = 32; off > 0; off >>= 1) {
            sx += __shfl_down(sx, off);
            sy += __shfl_down(sy, off);
        }
        __shared__ float rxs[4], rys[4];
        const int w = tid >> 6, lane = tid & 63;
        if (lane == 0) { rxs[w] = sx; rys[w] = sy; }
        __syncthreads();
        if (tid == 0) {
            float* meanws = (float*)(ws + WS_MEAN);
            meanws[b * 2 + 0] = (rxs[0] + rxs[1] + rxs[2] + rxs[3]) * (1.f / NA);
            meanws[b * 2 + 1] = (rys[0] + rys[1] + rys[2] + rys[3]) * (1.f / NA);
            out[b] = (float)NPAIR * pb2[0] + (float)NA * ab2[0];
        }
        return;
    }

    // ---- weight fragment packing ----
    _Float16* w0p = (_Float16*)(ws + WS_W0P);
    _Float16* w0a = (_Float16*)(ws + WS_W0A);
    _Float16* w1p = (_Float16*)(ws + WS_W1P);
    _Float16* w1a = (_Float16*)(ws + WS_W1A);

    for (int idx = tid; idx < 2048; idx += 256) {
        const int j = idx & 7, lane = (idx >> 3) & 63, nt = idx >> 9;
        const int k = ((lane >> 4) << 3) + j;
        const int col = nt * 16 + (lane & 15);
        float vp = 0.f, va = 0.f;
        if (k < 5) {
            vp = pW0[k * 64 + col];
            va = aW0[k * 64 + col];
        } else if (k >= 6 && k <= 9) {
            const int s = k - 6;
            float accp = 0.f, acca = 0.f;
#pragma unroll
            for (int e = 0; e < 16; e++) {
                float em = embed[s * 16 + e];
                accp += em * pW0[(5 + e) * 64 + col];
                acca += em * aW0[(5 + e) * 64 + col];
            }
            vp = accp; va = acca;
        } else if (k >= 10 && k <= 13) {
            const int s = k - 10;
            float accp = 0.f;
#pragma unroll
            for (int e = 0; e < 16; e++)
                accp += embed[s * 16 + e] * pW0[(21 + e) * 64 + col];
            vp = accp; va = 0.f;
        }
        w0p[idx] = (_Float16)vp;
        w0a[idx] = (_Float16)va;
    }
    for (int idx = tid; idx < 4096; idx += 256) {
        const int j = idx & 7, lane = (idx >> 3) & 63;
        const int ks = (idx >> 9) & 1, nt = idx >> 10;
        const int k = ks * 32 + ((lane >> 4) << 3) + j;
        const int col = nt * 16 + (lane & 15);
        w1p[idx] = (_Float16)pW1[k * 64 + col];
        w1a[idx] = (_Float16)aW1[k * 64 + col];
    }
}

// ---------------------------------------------------------------------------
// fused pair+atom MLP. Pair blocks bx<512 handle tiles {bx+512t} (4 or 3),
// block 512 handles the 4 atom tiles. Wave-private pipelines, no barriers.
// ---------------------------------------------------------------------------
__global__ __launch_bounds__(256, 4) void mlp_kernel(
    const float* __restrict__ positions,
    const int*   __restrict__ species,
    const float* __restrict__ efield,
    const float* __restrict__ ab0, const float* __restrict__ ab1,
    const float* __restrict__ aW2,
    const float* __restrict__ pb0, const float* __restrict__ pb1,
    const float* __restrict__ pW2,
    const char*  __restrict__ ws,
    float* __restrict__ out)
{
    const int b    = blockIdx.y;
    const int bx   = blockIdx.x;
    const bool is_atom = (bx == PAIR_BLOCKS);
    const int tid  = threadIdx.x;
    const int lane = tid & 63;
    const int wv   = tid >> 6;
    const int n16  = lane & 15;
    const int quad = lane >> 4;

    // 64 rows x 72 halves per wave; halves 0..31 = A (K=32), 0..63 = H after L0
    __shared__ __attribute__((aligned(16))) _Float16 Hbuf[4][64][72];
    _Float16 (*rows)[72] = Hbuf[wv];

    // ---- block-wide weight fragments (coalesced, once per block) ----
    const _Float16* w0w = (const _Float16*)(ws + (is_atom ? WS_W0A : WS_W0P));
    const _Float16* w1w = (const _Float16*)(ws + (is_atom ? WS_W1A : WS_W1P));
    half8 w0f[4], w1f[4][2];
#pragma unroll
    for (int nt = 0; nt < 4; nt++)
        w0f[nt] = *(const half8*)(w0w + (nt * 64 + lane) * 8);
#pragma unroll
    for (int nt = 0; nt < 4; nt++)
#pragma unroll
        for (int ks = 0; ks < 2; ks++)
            w1f[nt][ks] = *(const half8*)(w1w + ((nt * 2 + ks) * 64 + lane) * 8);

    const float* B0 = is_atom ? ab0 : pb0;
    const float* B1 = is_atom ? ab1 : pb1;
    const float* W2 = is_atom ? aW2 : pW2;
    float b0v[4], b1v[4], w2v[4];
#pragma unroll
    for (int nt = 0; nt < 4; nt++) {
        b0v[nt] = B0[nt * 16 + n16];
        b1v[nt] = B1[nt * 16 + n16];
        w2v[nt] = W2[nt * 16 + n16];
    }

    const float Ex = efield[b * 2 + 0];
    const float Ey = efield[b * 2 + 1];
    const float enorm = sqrtf(Ex * Ex + Ey * Ey);
    const float* meanws = (const float*)(ws + WS_MEAN);

    const int my_tiles = is_atom ? 4 : ((bx < PAIR_TILES - 3 * PAIR_BLOCKS) ? 4 : 3);

    float energy = 0.f;
    for (int t = 0; t < my_tiles; ++t) {
        // ---- build feature row (13 live halves of K=32) ----
        float f0, f1, f2, f3;
        uint64_t ohi, ohj;
        if (!is_atom) {
            const int tile = bx + t * PAIR_BLOCKS;
            const int p = tile * 256 + tid;
            float Df = (float)(2047 * 2047 - 8 * p);
            int i = (int)((2047.0f - sqrtf(Df)) * 0.5f);
            i = i < 0 ? 0 : (i > 1022 ? 1022 : i);
            while (i * (2047 - i) / 2 > p) --i;
            while ((i + 1) * (2046 - i) / 2 <= p) ++i;
            const int j = p - i * (2047 - i) / 2 + i + 1;
            const float2* pos = (const float2*)positions + b * NA;
            float2 pi = pos[i], pj = pos[j];
            f0 = pi.x - pj.x; f1 = pi.y - pj.y;           // mean cancels
            f2 = sqrtf(f0 * f0 + f1 * f1);
            float inv = __builtin_amdgcn_rcpf(fmaxf(f2, 1e-12f));
            f3 = (Ex * f0 + Ey * f1) * inv;
            ohi = 0x3C00ull << (species[b * NA + i] * 16);
            ohj = 0x3C00ull << (species[b * NA + j] * 16);
        } else {
            const int n = t * 256 + tid;
            float2 pn = ((const float2*)positions)[b * NA + n];
            f0 = pn.x - meanws[b * 2 + 0];
            f1 = pn.y - meanws[b * 2 + 1];
            f2 = Ex; f3 = Ey;
            ohi = 0x3C00ull << (species[b * NA + n] * 16);
            ohj = 0;
        }
        // halves: 0..4 = f0..f4(enorm), 5 = 0, 6..9 = oh_i, 10..13 = oh_j
        int4* dst = (int4*)&rows[lane][0];
        int4 lo, hi;
        lo.x = (int)pkf16(f0, f1);
        lo.y = (int)pkf16(f2, f3);
        lo.z = (int)pkf16(enorm, 0.f);
        lo.w = (int)(uint32_t)ohi;
        hi.x = (int)(uint32_t)(ohi >> 32);
        hi.y = (int)(uint32_t)ohj;
        hi.z = (int)(uint32_t)(ohj >> 32);
        hi.w = 0;
        dst[0] = lo;
        dst[1] = hi;
        dst[2] = make_int4(0, 0, 0, 0);   // halves 16..31 (K pad)
        dst[3] = make_int4(0, 0, 0, 0);

        // ---- 4 m-tiles: L0 (K=32) -> silu -> H -> L1 (K=64) -> energy ----
#pragma unroll
        for (int mt = 0; mt < 4; mt++) {
            const _Float16* arow = &rows[mt * 16 + n16][0];
            half8 a = *(const half8*)(arow + quad * 8);

            float4v acc[4];
#pragma unroll
            for (int nt = 0; nt < 4; nt++) {
                float4v c = {b0v[nt], b0v[nt], b0v[nt], b0v[nt]};
                acc[nt] = __builtin_amdgcn_mfma_f32_16x16x32_f16(a, w0f[nt], c, 0, 0, 0);
            }
            // C layout: row = quad*4 + r, col = nt*16 + n16
#pragma unroll
            for (int nt = 0; nt < 4; nt++)
#pragma unroll
                for (int r = 0; r < 4; r++)
                    rows[mt * 16 + quad * 4 + r][nt * 16 + n16] =
                        (_Float16)silu_f(acc[nt][r]);

            const _Float16* hrow = &rows[mt * 16 + n16][0];
            half8 h0 = *(const half8*)(hrow + quad * 8);
            half8 h1 = *(const half8*)(hrow + 32 + quad * 8);
            float4v acc2[4];
#pragma unroll
            for (int nt = 0; nt < 4; nt++) {
                float4v c = {b1v[nt], b1v[nt], b1v[nt], b1v[nt]};
                c = __builtin_amdgcn_mfma_f32_16x16x32_f16(h0, w1f[nt][0], c, 0, 0, 0);
                c = __builtin_amdgcn_mfma_f32_16x16x32_f16(h1, w1f[nt][1], c, 0, 0, 0);
                acc2[nt] = c;
            }
#pragma unroll
            for (int nt = 0; nt < 4; nt++)
#pragma unroll
                for (int r = 0; r < 4; r++)
                    energy += silu_f(acc2[nt][r]) * w2v[nt];
        }
    }

    // ---- block reduction -> one atomicAdd per block ----
#pragma unroll
    for (int off = 32; off > 0; off >>= 1)
        energy += __shfl_down(energy, off);
    __shared__ float wsum[4];
    if (lane == 0) wsum[wv] = energy;
    __syncthreads();
    if (tid == 0)
        atomicAdd(&out[b], wsum[0] + wsum[1] + wsum[2] + wsum[3]);
}

// ---------------------------------------------------------------------------
extern "C" void kernel_launch(void* const* d_in, const int* in_sizes, int n_in,
                              void* d_out, int out_size, void* d_ws, size_t ws_size,
                              hipStream_t stream) {
    const float* positions = (const float*)d_in[0];
    const int*   species   = (const int*)  d_in[1];
    const float* efield    = (const float*)d_in[2];
    const float* embed     = (const float*)d_in[3];
    const float* aW0 = (const float*)d_in[4];
    const float* ab0 = (const float*)d_in[5];
    const float* aW1 = (const float*)d_in[6];
    const float* ab1 = (const float*)d_in[7];
    const float* aW2 = (const float*)d_in[8];
    const float* ab2 = (const float*)d_in[9];
    const float* pW0 = (const float*)d_in[10];
    const float* pb0 = (const float*)d_in[11];
    const float* pW1 = (const float*)d_in[12];
    const float* pb1 = (const float*)d_in[13];
    const float* pW2 = (const float*)d_in[14];
    const float* pb2 = (const float*)d_in[15];
    float* outp = (float*)d_out;
    char*  ws   = (char*)d_ws;

    prep_kernel<<<dim3(5), dim3(256), 0, stream>>>(
        positions, embed, aW0, aW1, ab2, pW0, pW1, pb2, ws, outp);
    mlp_kernel<<<dim3(GRID_X, NBATCH), dim3(256), 0, stream>>>(
        positions, species, efield,
        ab0, ab1, aW2, pb0, pb1, pW2,
        ws, outp);
}